// Round 4
// baseline (1074.745 us; speedup 1.0000x reference)
//
#include <hip/hip_runtime.h>
#include <hip/hip_bf16.h>

using bf16 = __hip_bfloat16;
typedef unsigned int uint;
typedef unsigned short ushort;

// Shapes: B=2, S=512, SD=512, P=256, PD=128, AD=64, H=256

__device__ __forceinline__ float lbf(ushort u) { return __uint_as_float(((uint)u) << 16); }
__device__ __forceinline__ float bfraw(uint u) { return __uint_as_float(u << 16); }
__device__ __forceinline__ ushort f2bf(float f) {
    bf16 h = __float2bfloat16(f);
    return *reinterpret_cast<ushort*>(&h);
}
__device__ __forceinline__ uint packbf(float a, float b) {
    return (uint)f2bf(a) | ((uint)f2bf(b) << 16);
}

// dtype-agnostic global load/store: F32=true -> float*, else bf16(ushort)*
template<bool F32>
__device__ __forceinline__ float ld(const void* p, size_t i) {
    if constexpr (F32) return ((const float*)p)[i];
    else return lbf(((const ushort*)p)[i]);
}
template<bool F32>
__device__ __forceinline__ void st(void* p, size_t i, float v) {
    if constexpr (F32) ((float*)p)[i] = v;
    else ((ushort*)p)[i] = f2bf(v);
}

// ---------------------------------------------------------------------------
// Probe: sn_g is all ones. f32 word0 = 0x3F800000 ; bf16 pair = 0x3F803F80.
// flag = 1 -> f32 tensors, 0 -> bf16 tensors.
// ---------------------------------------------------------------------------
__global__ void k_detect(const uint* __restrict__ w, int* __restrict__ flag)
{
    if (threadIdx.x == 0) *flag = (w[0] == 0x3F803F80u) ? 0 : 1;
}

// ---------------------------------------------------------------------------
// A: LayerNorm(seq) over SD=512 + avg-pool row pairs -> x2 (f32 ws)
// ---------------------------------------------------------------------------
template<bool F32>
__device__ __forceinline__ void ln_pool_body(
    const void* seq, const void* g, const void* be, float* x2)
{
    __shared__ float red[4][4];
    int bp = blockIdx.x;
    int t  = threadIdx.x;
    size_t rb = (size_t)(bp * 2) * 512;

    float a0 = ld<F32>(seq, rb + t),       a1 = ld<F32>(seq, rb + t + 256);
    float c0 = ld<F32>(seq, rb + 512 + t), c1 = ld<F32>(seq, rb + 512 + t + 256);

    float s0 = a0 + a1, q0 = a0 * a0 + a1 * a1;
    float s1 = c0 + c1, q1 = c0 * c0 + c1 * c1;
#pragma unroll
    for (int off = 32; off; off >>= 1) {
        s0 += __shfl_xor(s0, off); q0 += __shfl_xor(q0, off);
        s1 += __shfl_xor(s1, off); q1 += __shfl_xor(q1, off);
    }
    int w = t >> 6, l = t & 63;
    if (l == 0) { red[0][w] = s0; red[1][w] = q0; red[2][w] = s1; red[3][w] = q1; }
    __syncthreads();
    s0 = red[0][0] + red[0][1] + red[0][2] + red[0][3];
    q0 = red[1][0] + red[1][1] + red[1][2] + red[1][3];
    s1 = red[2][0] + red[2][1] + red[2][2] + red[2][3];
    q1 = red[3][0] + red[3][1] + red[3][2] + red[3][3];

    const float inv = 1.0f / 512.0f;
    float mu0 = s0 * inv, var0 = q0 * inv - mu0 * mu0, rs0 = rsqrtf(var0 + 1e-5f);
    float mu1 = s1 * inv, var1 = q1 * inv - mu1 * mu1, rs1 = rsqrtf(var1 + 1e-5f);

    float g0 = ld<F32>(g, t), g1 = ld<F32>(g, t + 256);
    float e0 = ld<F32>(be, t), e1 = ld<F32>(be, t + 256);

    float o0 = 0.5f * ((a0 - mu0) * rs0 * g0 + e0 + (c0 - mu1) * rs1 * g0 + e0);
    float o1 = 0.5f * ((a1 - mu0) * rs0 * g1 + e1 + (c1 - mu1) * rs1 * g1 + e1);

    float* xo = x2 + (size_t)bp * 512;
    xo[t] = o0; xo[t + 256] = o1;
}
__global__ __launch_bounds__(256) void k_ln_pool(
    const void* seq, const void* g, const void* be, float* x2, const int* flag)
{
    if (*flag) ln_pool_body<true>(seq, g, be, x2);
    else       ln_pool_body<false>(seq, g, be, x2);
}

// ---------------------------------------------------------------------------
// B: A2 = (x@Wq + gelu(x)@Wyq)@Wout + bout ; C2 = (x@Wk + gelu(x)@Wyk)@Wout
// ---------------------------------------------------------------------------
template<bool F32>
__device__ __forceinline__ void proj_body(
    const float* x2, const void* Wq, const void* Wk,
    const void* Wyq, const void* Wyk, const void* Wout, const void* bout,
    float* a2, float* c2)
{
    __shared__ float xr[512], gxr[512], ar[128], cr[128];
    int row = blockIdx.x;
    int t   = threadIdx.x;

    for (int u = t; u < 512; u += 128) {
        float v = x2[(size_t)row * 512 + u];
        xr[u]  = v;
        gxr[u] = 0.5f * v * (1.0f + erff(v * 0.70710678118654752f));
    }
    __syncthreads();

    float a = 0.f, c = 0.f;
    for (int s = 0; s < 512; s++) {
        float xs = xr[s], gs = gxr[s];
        a += xs * ld<F32>(Wq, s * 128 + t) + gs * ld<F32>(Wyq, s * 128 + t);
        c += xs * ld<F32>(Wk, s * 128 + t) + gs * ld<F32>(Wyk, s * 128 + t);
    }
    ar[t] = a; cr[t] = c;
    __syncthreads();

    float A = ld<F32>(bout, t), C = 0.f;
    for (int u = 0; u < 128; u++) {
        float wv = ld<F32>(Wout, u * 128 + t);
        A += ar[u] * wv;
        C += cr[u] * wv;
    }
    a2[(size_t)row * 128 + t] = A;
    c2[(size_t)row * 128 + t] = C;
}
__global__ __launch_bounds__(128) void k_proj(
    const float* x2, const void* Wq, const void* Wk,
    const void* Wyq, const void* Wyk, const void* Wout, const void* bout,
    float* a2, float* c2, const int* flag)
{
    if (*flag) proj_body<true>(x2, Wq, Wk, Wyq, Wyk, Wout, bout, a2, c2);
    else       proj_body<false>(x2, Wq, Wk, Wyq, Wyk, Wout, bout, a2, c2);
}

// ---------------------------------------------------------------------------
// W: Wd2 = Wdist(3x128) @ Wout(128x128)
// ---------------------------------------------------------------------------
template<bool F32>
__device__ __forceinline__ void wd2_body(const void* Wdist, const void* Wout, float* wd2)
{
    int t = threadIdx.x;
#pragma unroll
    for (int f = 0; f < 3; f++) {
        float acc = 0.f;
        for (int u = 0; u < 128; u++)
            acc += ld<F32>(Wdist, f * 128 + u) * ld<F32>(Wout, u * 128 + t);
        wd2[f * 128 + t] = acc;
    }
}
__global__ __launch_bounds__(128) void k_wd2(
    const void* Wdist, const void* Wout, float* wd2, const int* flag)
{
    if (*flag) wd2_body<true>(Wdist, Wout, wd2);
    else       wd2_body<false>(Wdist, Wout, wd2);
}

// ---------------------------------------------------------------------------
// C: x[b,i,j,d] = pair + A2[b,i,d] + C2[b,j,d] + feats(i,j)·Wd2[:,d] -> d_out
// ---------------------------------------------------------------------------
template<bool F32>
__device__ __forceinline__ void assemble_body(
    const void* pair, const float* a2, const float* c2, const float* wd2,
    void* xout)
{
    size_t idx = (size_t)blockIdx.x * 256 + threadIdx.x;
    int d = (int)(idx & 127);
    size_t r = idx >> 7;
    int j = (int)(r & 255); r >>= 8;
    int i = (int)(r & 255);
    int b = (int)(r >> 8);

    float ds = fabsf((float)(i - j)) * (1.0f / 255.0f);
    float sg = (float)((i > j) - (i < j));
    float ex = __expf(-ds);

    float v = ld<F32>(pair, idx)
            + a2[(size_t)(b * 256 + i) * 128 + d]
            + c2[(size_t)(b * 256 + j) * 128 + d]
            + ds * wd2[d] + sg * wd2[128 + d] + ex * wd2[256 + d];
    st<F32>(xout, idx, v);
}
__global__ __launch_bounds__(256) void k_assemble(
    const void* pair, const float* a2, const float* c2, const float* wd2,
    void* xout, const int* flag)
{
    if (*flag) assemble_body<true>(pair, a2, c2, wd2, xout);
    else       assemble_body<false>(pair, a2, c2, wd2, xout);
}

// ---------------------------------------------------------------------------
// E (fused): per (b,i) slice [256x128]: LN -> q/k/v in LDS -> online-softmax
// attention -> x += o@Wro + bro.  grid=512, block=256.
// LDS (bytes): k_s 0..32768 | v_s 32768..65536 | q_s/o_s 65536..98304 |
//              wq 98304 wk 114688 wv 131072 (..147456) | yn 147456..155648
// phase-4 overlays wro_s(f32,32KB) on k_s.
// ---------------------------------------------------------------------------
template<bool F32>
__device__ __forceinline__ void attn_body(
    void* x,
    const void* rn_g, const void* rn_b,
    const void* Wrq, const void* Wrk, const void* Wrv, const void* brv,
    const void* Wro, const void* bro,
    unsigned char* smem)
{
    ushort* k_s = (ushort*)smem;
    ushort* v_s = (ushort*)(smem + 32768);
    ushort* q_s = (ushort*)(smem + 65536);
    ushort* wqb = (ushort*)(smem + 98304);
    ushort* wkb = wqb + 8192;
    ushort* wvb = wkb + 8192;
    ushort* ynb = (ushort*)(smem + 147456);

    int tid = threadIdx.x;
    int w = tid >> 6, l = tid & 63;
    size_t base = (size_t)blockIdx.x * 32768;   // slice [256][128]

    // stage q/k/v weights to LDS (bf16 internal), layout [128][64] as global
    for (int gi = tid; gi < 8192; gi += 256) {
        wqb[gi] = f2bf(ld<F32>(Wrq, gi));
        wkb[gi] = f2bf(ld<F32>(Wrk, gi));
        wvb[gi] = f2bf(ld<F32>(Wrv, gi));
    }
    float gl0 = ld<F32>(rn_g, l), gl1 = ld<F32>(rn_g, l + 64);
    float el0 = ld<F32>(rn_b, l), el1 = ld<F32>(rn_b, l + 64);
    float bv  = ld<F32>(brv, l);
    __syncthreads();

    // Phase 1: LN + QKV. Wave w owns rows [w*64,(w+1)*64), 8 at a time.
    for (int batch = 0; batch < 8; batch++) {
        int r0 = w * 64 + batch * 8;
#pragma unroll
        for (int rr = 0; rr < 8; rr++) {
            size_t ro = base + (size_t)(r0 + rr) * 128;
            float x0 = ld<F32>(x, ro + l);
            float x1 = ld<F32>(x, ro + l + 64);
            float s = x0 + x1, q = x0 * x0 + x1 * x1;
#pragma unroll
            for (int off = 32; off; off >>= 1) { s += __shfl_xor(s, off); q += __shfl_xor(q, off); }
            float mu = s * (1.0f / 128.0f);
            float var = q * (1.0f / 128.0f) - mu * mu;
            float rs = rsqrtf(var + 1e-5f);
            ynb[(w * 8 + rr) * 128 + l]      = f2bf((x0 - mu) * rs * gl0 + el0);
            ynb[(w * 8 + rr) * 128 + l + 64] = f2bf((x1 - mu) * rs * gl1 + el1);
        }
        float aq[8], ak[8], av[8];
#pragma unroll
        for (int i = 0; i < 8; i++) { aq[i] = 0.f; ak[i] = 0.f; av[i] = 0.f; }
        for (int u = 0; u < 128; u++) {
            float wqv = lbf(wqb[u * 64 + l]);
            float wkv = lbf(wkb[u * 64 + l]);
            float wvv = lbf(wvb[u * 64 + l]);
#pragma unroll
            for (int rr = 0; rr < 8; rr++) {
                float y = lbf(ynb[(w * 8 + rr) * 128 + u]);  // uniform addr -> broadcast
                aq[rr] += y * wqv;
                ak[rr] += y * wkv;
                av[rr] += y * wvv;
            }
        }
#pragma unroll
        for (int rr = 0; rr < 8; rr++) {
            int row = r0 + rr;
            q_s[row * 64 + l] = f2bf(aq[rr]);
            k_s[row * 64 + l] = f2bf(ak[rr]);
            v_s[row * 64 + l] = f2bf(av[rr] + bv);
        }
    }
    __syncthreads();

    // Phase 2: thread = query row tid; scale 1/sqrt(64) folded into q.
    float qf[64];
    {
        const uint4* qrow = (const uint4*)(q_s + tid * 64);
#pragma unroll
        for (int c8 = 0; c8 < 8; c8++) {
            uint4 v = qrow[c8];
            qf[c8 * 8 + 0] = bfraw(v.x & 0xffffu) * 0.125f;
            qf[c8 * 8 + 1] = bfraw(v.x >> 16)     * 0.125f;
            qf[c8 * 8 + 2] = bfraw(v.y & 0xffffu) * 0.125f;
            qf[c8 * 8 + 3] = bfraw(v.y >> 16)     * 0.125f;
            qf[c8 * 8 + 4] = bfraw(v.z & 0xffffu) * 0.125f;
            qf[c8 * 8 + 5] = bfraw(v.z >> 16)     * 0.125f;
            qf[c8 * 8 + 6] = bfraw(v.w & 0xffffu) * 0.125f;
            qf[c8 * 8 + 7] = bfraw(v.w >> 16)     * 0.125f;
        }
    }
    float m = -INFINITY, lsum = 0.f;
    float acc[64];
#pragma unroll
    for (int d2 = 0; d2 < 64; d2++) acc[d2] = 0.f;

    for (int s = 0; s < 256; s++) {
        const uint4* kr = (const uint4*)(k_s + s * 64);   // broadcast
        float p0 = 0.f, p1 = 0.f, p2 = 0.f, p3 = 0.f;
        float p4 = 0.f, p5 = 0.f, p6 = 0.f, p7 = 0.f;
#pragma unroll
        for (int c8 = 0; c8 < 8; c8++) {
            uint4 kv = kr[c8];
            p0 += qf[c8 * 8 + 0] * bfraw(kv.x & 0xffffu);
            p1 += qf[c8 * 8 + 1] * bfraw(kv.x >> 16);
            p2 += qf[c8 * 8 + 2] * bfraw(kv.y & 0xffffu);
            p3 += qf[c8 * 8 + 3] * bfraw(kv.y >> 16);
            p4 += qf[c8 * 8 + 4] * bfraw(kv.z & 0xffffu);
            p5 += qf[c8 * 8 + 5] * bfraw(kv.z >> 16);
            p6 += qf[c8 * 8 + 6] * bfraw(kv.w & 0xffffu);
            p7 += qf[c8 * 8 + 7] * bfraw(kv.w >> 16);
        }
        float lgt = ((p0 + p1) + (p2 + p3)) + ((p4 + p5) + (p6 + p7));
        if (lgt > m) {
            float corr = __expf(m - lgt);
            lsum *= corr;
#pragma unroll
            for (int d2 = 0; d2 < 64; d2++) acc[d2] *= corr;
            m = lgt;
        }
        float p = __expf(lgt - m);
        lsum += p;
        const uint4* vr = (const uint4*)(v_s + s * 64);   // broadcast
#pragma unroll
        for (int c8 = 0; c8 < 8; c8++) {
            uint4 vv = vr[c8];
            acc[c8 * 8 + 0] += p * bfraw(vv.x & 0xffffu);
            acc[c8 * 8 + 1] += p * bfraw(vv.x >> 16);
            acc[c8 * 8 + 2] += p * bfraw(vv.y & 0xffffu);
            acc[c8 * 8 + 3] += p * bfraw(vv.y >> 16);
            acc[c8 * 8 + 4] += p * bfraw(vv.z & 0xffffu);
            acc[c8 * 8 + 5] += p * bfraw(vv.z >> 16);
            acc[c8 * 8 + 6] += p * bfraw(vv.w & 0xffffu);
            acc[c8 * 8 + 7] += p * bfraw(vv.w >> 16);
        }
    }
    __syncthreads();   // all done with k_s/v_s/q_s

    // Phase 3: o (normalized bf16) -> q_s row tid (own row only); Wro f32 -> k_s
    {
        float rl = 1.0f / lsum;
        uint4* osrow = (uint4*)(q_s + tid * 64);
#pragma unroll
        for (int c8 = 0; c8 < 8; c8++) {
            uint4 o;
            o.x = packbf(acc[c8 * 8 + 0] * rl, acc[c8 * 8 + 1] * rl);
            o.y = packbf(acc[c8 * 8 + 2] * rl, acc[c8 * 8 + 3] * rl);
            o.z = packbf(acc[c8 * 8 + 4] * rl, acc[c8 * 8 + 5] * rl);
            o.w = packbf(acc[c8 * 8 + 6] * rl, acc[c8 * 8 + 7] * rl);
            osrow[c8] = o;
        }
        float* wro_s = (float*)smem;
        for (int i2 = tid; i2 < 8192; i2 += 256) wro_s[i2] = ld<F32>(Wro, i2);
    }
    __syncthreads();

    // Phase 4: x += o @ Wro + bro.  Thread owns col d=tid&127, rows rh,rh+2,...
    {
        const float* wro_s = (const float*)smem;
        int d = tid & 127;
        int rh = tid >> 7;
        float brod = ld<F32>(bro, d);
        float wro_r[64];
#pragma unroll
        for (int c = 0; c < 64; c++) wro_r[c] = wro_s[c * 128 + d];
        for (int kk = 0; kk < 128; kk++) {
            int r = kk * 2 + rh;
            const uint4* orow = (const uint4*)(q_s + r * 64);  // broadcast
            float v0 = 0.f, v1 = 0.f, v2 = 0.f, v3 = 0.f;
#pragma unroll
            for (int c8 = 0; c8 < 8; c8++) {
                uint4 ov = orow[c8];
                v0 += bfraw(ov.x & 0xffffu) * wro_r[c8 * 8 + 0];
                v1 += bfraw(ov.x >> 16)     * wro_r[c8 * 8 + 1];
                v2 += bfraw(ov.y & 0xffffu) * wro_r[c8 * 8 + 2];
                v3 += bfraw(ov.y >> 16)     * wro_r[c8 * 8 + 3];
                v0 += bfraw(ov.z & 0xffffu) * wro_r[c8 * 8 + 4];
                v1 += bfraw(ov.z >> 16)     * wro_r[c8 * 8 + 5];
                v2 += bfraw(ov.w & 0xffffu) * wro_r[c8 * 8 + 6];
                v3 += bfraw(ov.w >> 16)     * wro_r[c8 * 8 + 7];
            }
            size_t off = base + (size_t)r * 128 + d;
            st<F32>(x, off, ld<F32>(x, off) + brod + ((v0 + v1) + (v2 + v3)));
        }
    }
}
__global__ __launch_bounds__(256) void k_attn_f(
    void* x, const void* rn_g, const void* rn_b,
    const void* Wrq, const void* Wrk, const void* Wrv, const void* brv,
    const void* Wro, const void* bro, const int* flag)
{
    __shared__ __align__(16) unsigned char smem[155648];
    if (*flag) attn_body<true>(x, rn_g, rn_b, Wrq, Wrk, Wrv, brv, Wro, bro, smem);
    else       attn_body<false>(x, rn_g, rn_b, Wrq, Wrk, Wrv, brv, Wro, bro, smem);
}

// ---------------------------------------------------------------------------
// F (tiled MLP): 16 rows/block, 8192 blocks. x += relu(LN(x)@W1+b1)@W2 + b2.
// ---------------------------------------------------------------------------
template<bool F32>
__device__ __forceinline__ void mlp_body(
    void* x, const void* mn_g, const void* mn_b,
    const void* W1, const void* b1, const void* W2, const void* b2,
    ushort* ynm, ushort* hbuf)
{
    int tid = threadIdx.x, w = tid >> 6, l = tid & 63;
    size_t rbase = (size_t)blockIdx.x * 16;

    // Phase A: LN
    {
        float gl0 = ld<F32>(mn_g, l), gl1 = ld<F32>(mn_g, l + 64);
        float el0 = ld<F32>(mn_b, l), el1 = ld<F32>(mn_b, l + 64);
#pragma unroll
        for (int rr = 0; rr < 4; rr++) {
            int lr = w * 4 + rr;
            size_t ro = (rbase + lr) * 128;
            float x0 = ld<F32>(x, ro + l), x1 = ld<F32>(x, ro + l + 64);
            float s = x0 + x1, q = x0 * x0 + x1 * x1;
#pragma unroll
            for (int off = 32; off; off >>= 1) { s += __shfl_xor(s, off); q += __shfl_xor(q, off); }
            float mu = s * (1.0f / 128.0f);
            float var = q * (1.0f / 128.0f) - mu * mu;
            float rs = rsqrtf(var + 1e-5f);
            ynm[lr * 128 + l]      = f2bf((x0 - mu) * rs * gl0 + el0);
            ynm[lr * 128 + l + 64] = f2bf((x1 - mu) * rs * gl1 + el1);
        }
    }
    __syncthreads();

    // Phase B: h = relu(yn@W1 + b1). Thread: cols (2ch,2ch+1), rows g*8..+8.
    {
        int ch = tid & 127;
        int g  = tid >> 7;
        float hb0 = ld<F32>(b1, 2 * ch), hb1 = ld<F32>(b1, 2 * ch + 1);
        float accB[16];
#pragma unroll
        for (int i = 0; i < 8; i++) { accB[i * 2] = hb0; accB[i * 2 + 1] = hb1; }
        for (int u = 0; u < 128; u += 2) {
            float wa0 = ld<F32>(W1, (size_t)u * 256 + 2 * ch);
            float wa1 = ld<F32>(W1, (size_t)u * 256 + 2 * ch + 1);
            float wb0 = ld<F32>(W1, (size_t)(u + 1) * 256 + 2 * ch);
            float wb1 = ld<F32>(W1, (size_t)(u + 1) * 256 + 2 * ch + 1);
#pragma unroll
            for (int rr = 0; rr < 8; rr++) {
                uint yv = *(const uint*)(ynm + (g * 8 + rr) * 128 + u);  // broadcast
                float y0 = bfraw(yv & 0xffffu), y1 = bfraw(yv >> 16);
                accB[rr * 2 + 0] += y0 * wa0 + y1 * wb0;
                accB[rr * 2 + 1] += y0 * wa1 + y1 * wb1;
            }
        }
#pragma unroll
        for (int rr = 0; rr < 8; rr++) {
            uint hp = packbf(fmaxf(accB[rr * 2], 0.f), fmaxf(accB[rr * 2 + 1], 0.f));
            *(uint*)(hbuf + (g * 8 + rr) * 256 + 2 * ch) = hp;
        }
    }
    __syncthreads();

    // Phase C: out = x + h@W2 + b2. Thread: cols (2dh,2dh+1), rows g2*4..+4.
    {
        int dh = tid & 63;
        int g2 = tid >> 6;
        float ob0 = ld<F32>(b2, 2 * dh), ob1 = ld<F32>(b2, 2 * dh + 1);
        float accC[8];
#pragma unroll
        for (int i = 0; i < 4; i++) { accC[i * 2] = ob0; accC[i * 2 + 1] = ob1; }
        for (int c = 0; c < 256; c += 2) {
            float wa0 = ld<F32>(W2, (size_t)c * 128 + 2 * dh);
            float wa1 = ld<F32>(W2, (size_t)c * 128 + 2 * dh + 1);
            float wb0 = ld<F32>(W2, (size_t)(c + 1) * 128 + 2 * dh);
            float wb1 = ld<F32>(W2, (size_t)(c + 1) * 128 + 2 * dh + 1);
#pragma unroll
            for (int rr = 0; rr < 4; rr++) {
                uint hv = *(const uint*)(hbuf + (g2 * 4 + rr) * 256 + c);  // broadcast
                float h0 = bfraw(hv & 0xffffu), h1 = bfraw(hv >> 16);
                accC[rr * 2 + 0] += h0 * wa0 + h1 * wb0;
                accC[rr * 2 + 1] += h0 * wa1 + h1 * wb1;
            }
        }
#pragma unroll
        for (int rr = 0; rr < 4; rr++) {
            size_t off = (rbase + g2 * 4 + rr) * 128 + 2 * dh;
            st<F32>(x, off,     ld<F32>(x, off)     + accC[rr * 2 + 0]);
            st<F32>(x, off + 1, ld<F32>(x, off + 1) + accC[rr * 2 + 1]);
        }
    }
}
__global__ __launch_bounds__(256) void k_mlp_t(
    void* x, const void* mn_g, const void* mn_b,
    const void* W1, const void* b1, const void* W2, const void* b2,
    const int* flag)
{
    __shared__ ushort ynm[16 * 128];
    __shared__ ushort hbuf[16 * 256];
    if (*flag) mlp_body<true>(x, mn_g, mn_b, W1, b1, W2, b2, ynm, hbuf);
    else       mlp_body<false>(x, mn_g, mn_b, W1, b1, W2, b2, ynm, hbuf);
}

// ---------------------------------------------------------------------------
extern "C" void kernel_launch(void* const* d_in, const int* in_sizes, int n_in,
                              void* d_out, int out_size, void* d_ws, size_t ws_size,
                              hipStream_t stream)
{
    const void* seq   = d_in[0];
    const void* pair  = d_in[1];
    const void* sn_g  = d_in[2];
    const void* sn_b  = d_in[3];
    const void* Wq    = d_in[4];
    const void* Wk    = d_in[5];
    const void* Wyq   = d_in[6];
    const void* Wyk   = d_in[7];
    const void* Wdist = d_in[8];
    const void* Wout  = d_in[9];
    const void* bout  = d_in[10];
    const void* rn_g  = d_in[11];
    const void* rn_b  = d_in[12];
    const void* Wrq   = d_in[13];
    const void* Wrk   = d_in[14];
    const void* Wrv   = d_in[15];
    const void* brv   = d_in[16];
    const void* Wro   = d_in[17];
    const void* bro   = d_in[18];
    const void* mn_g  = d_in[19];
    const void* mn_b  = d_in[20];
    const void* W1    = d_in[21];
    const void* b1    = d_in[22];
    const void* W2    = d_in[23];
    const void* b2    = d_in[24];
    (void)in_sizes; (void)n_in; (void)out_size; (void)ws_size;

    // ws: ~1.55 MB used
    int*   flag = (int*)d_ws;
    float* x2   = (float*)d_ws + 64;     // [2,256,512]  262144 f32
    float* a2   = x2 + 262144;           // [2,256,128]   65536 f32
    float* c2   = a2 + 65536;            // [2,256,128]   65536 f32
    float* wd2  = c2 + 65536;            // [3,128]         384 f32 (+pad)
    void*  xres = d_out;                 // residual stream, native dtype

    k_detect  <<<1,     64,  0, stream>>>((const uint*)sn_g, flag);
    k_ln_pool <<<512,   256, 0, stream>>>(seq, sn_g, sn_b, x2, flag);
    k_proj    <<<512,   128, 0, stream>>>(x2, Wq, Wk, Wyq, Wyk, Wout, bout, a2, c2, flag);
    k_wd2     <<<1,     128, 0, stream>>>(Wdist, Wout, wd2, flag);
    k_assemble<<<65536, 256, 0, stream>>>(pair, a2, c2, wd2, xres, flag);
    k_attn_f  <<<512,   256, 0, stream>>>(xres, rn_g, rn_b, Wrq, Wrk, Wrv, brv, Wro, bro, flag);
    k_mlp_t   <<<8192,  256, 0, stream>>>(xres, mn_g, mn_b, W1, b1, W2, b2, flag);
}

// Round 6
// 596.642 us; speedup vs baseline: 1.8013x; 1.8013x over previous
//
#include <hip/hip_runtime.h>
#include <hip/hip_bf16.h>

using bf16 = __hip_bfloat16;
typedef unsigned int uint;
typedef unsigned short ushort;
typedef __attribute__((ext_vector_type(8))) short bf16x8;
typedef __attribute__((ext_vector_type(4))) float f32x4;

// Shapes: B=2, S=512, SD=512, P=256, PD=128, AD=64, H=256
// All global tensors are f32 (verified: WRITE_SIZE of full-tensor store = 4B/elem).

__device__ __forceinline__ float bfraw(uint u) { return __uint_as_float(u << 16); }
__device__ __forceinline__ ushort f2bf(float f) {
    bf16 h = __float2bfloat16(f);
    return *reinterpret_cast<ushort*>(&h);
}
__device__ __forceinline__ uint packbf(float a, float b) {
    return (uint)f2bf(a) | ((uint)f2bf(b) << 16);
}

#define MFMA_B16(a, b, c) __builtin_amdgcn_mfma_f32_16x16x32_bf16((a), (b), (c), 0, 0, 0)

// ---------------------------------------------------------------------------
// A: LayerNorm(seq) over SD=512 + avg-pool row pairs -> x2 f32. 512 blocks.
// ---------------------------------------------------------------------------
__global__ __launch_bounds__(256) void k_ln_pool(
    const float* __restrict__ seq, const float* __restrict__ g,
    const float* __restrict__ be, float* __restrict__ x2)
{
    __shared__ float red[4][4];
    int bp = blockIdx.x;
    int t  = threadIdx.x;
    const float* r0 = seq + (size_t)(bp * 2) * 512;
    const float* r1 = r0 + 512;

    float a0 = r0[t], a1 = r0[t + 256];
    float c0 = r1[t], c1 = r1[t + 256];

    float s0 = a0 + a1, q0 = a0 * a0 + a1 * a1;
    float s1 = c0 + c1, q1 = c0 * c0 + c1 * c1;
#pragma unroll
    for (int off = 32; off; off >>= 1) {
        s0 += __shfl_xor(s0, off); q0 += __shfl_xor(q0, off);
        s1 += __shfl_xor(s1, off); q1 += __shfl_xor(q1, off);
    }
    int w = t >> 6, l = t & 63;
    if (l == 0) { red[0][w] = s0; red[1][w] = q0; red[2][w] = s1; red[3][w] = q1; }
    __syncthreads();
    s0 = red[0][0] + red[0][1] + red[0][2] + red[0][3];
    q0 = red[1][0] + red[1][1] + red[1][2] + red[1][3];
    s1 = red[2][0] + red[2][1] + red[2][2] + red[2][3];
    q1 = red[3][0] + red[3][1] + red[3][2] + red[3][3];

    const float inv = 1.0f / 512.0f;
    float mu0 = s0 * inv, var0 = q0 * inv - mu0 * mu0, rs0 = rsqrtf(var0 + 1e-5f);
    float mu1 = s1 * inv, var1 = q1 * inv - mu1 * mu1, rs1 = rsqrtf(var1 + 1e-5f);

    float g0 = g[t], g1 = g[t + 256];
    float e0 = be[t], e1 = be[t + 256];

    float o0 = 0.5f * ((a0 - mu0) * rs0 * g0 + e0 + (c0 - mu1) * rs1 * g0 + e0);
    float o1 = 0.5f * ((a1 - mu0) * rs0 * g1 + e1 + (c1 - mu1) * rs1 * g1 + e1);

    float* xo = x2 + (size_t)bp * 512;
    xo[t] = o0; xo[t + 256] = o1;
}

// ---------------------------------------------------------------------------
// B: A2 = (x@Wq + gelu(x)@Wyq)@Wout + bout ; C2 = (x@Wk + gelu(x)@Wyk)@Wout
// ---------------------------------------------------------------------------
__global__ __launch_bounds__(128) void k_proj(
    const float* __restrict__ x2,
    const float* __restrict__ Wq, const float* __restrict__ Wk,
    const float* __restrict__ Wyq, const float* __restrict__ Wyk,
    const float* __restrict__ Wout, const float* __restrict__ bout,
    float* __restrict__ a2, float* __restrict__ c2)
{
    __shared__ float xr[512], gxr[512], ar[128], cr[128];
    int row = blockIdx.x;
    int t   = threadIdx.x;

    for (int u = t; u < 512; u += 128) {
        float v = x2[(size_t)row * 512 + u];
        xr[u]  = v;
        gxr[u] = 0.5f * v * (1.0f + erff(v * 0.70710678118654752f));
    }
    __syncthreads();

    float a = 0.f, c = 0.f;
    for (int s = 0; s < 512; s++) {
        float xs = xr[s], gs = gxr[s];
        a += xs * Wq[s * 128 + t] + gs * Wyq[s * 128 + t];
        c += xs * Wk[s * 128 + t] + gs * Wyk[s * 128 + t];
    }
    ar[t] = a; cr[t] = c;
    __syncthreads();

    float A = bout[t], C = 0.f;
    for (int u = 0; u < 128; u++) {
        float wv = Wout[u * 128 + t];
        A += ar[u] * wv;
        C += cr[u] * wv;
    }
    a2[(size_t)row * 128 + t] = A;
    c2[(size_t)row * 128 + t] = C;
}

// ---------------------------------------------------------------------------
// W: Wd2 = Wdist(3x128) @ Wout(128x128)
// ---------------------------------------------------------------------------
__global__ __launch_bounds__(128) void k_wd2(
    const float* __restrict__ Wdist, const float* __restrict__ Wout,
    float* __restrict__ wd2)
{
    int t = threadIdx.x;
#pragma unroll
    for (int f = 0; f < 3; f++) {
        float acc = 0.f;
        for (int u = 0; u < 128; u++)
            acc += Wdist[f * 128 + u] * Wout[u * 128 + t];
        wd2[f * 128 + t] = acc;
    }
}

// ---------------------------------------------------------------------------
// WT prep: wT[c][k] (bf16, [64][128]) = W[k][c] (f32, [128][64]) for Wrq/Wrk/Wrv
// ---------------------------------------------------------------------------
__global__ __launch_bounds__(512) void k_wt(
    const float* __restrict__ Wrq, const float* __restrict__ Wrk,
    const float* __restrict__ Wrv, ushort* __restrict__ wqT,
    ushort* __restrict__ wkT, ushort* __restrict__ wvT)
{
    int idx = blockIdx.x * 512 + threadIdx.x;       // 0 .. 3*8192
    int m = idx >> 13;
    int e = idx & 8191;
    int c = e >> 7, k = e & 127;
    const float* W = (m == 0) ? Wrq : (m == 1) ? Wrk : Wrv;
    ushort* T = (m == 0) ? wqT : (m == 1) ? wkT : wvT;
    T[e] = f2bf(W[k * 64 + c]);
}

// ---------------------------------------------------------------------------
// C: x[b,i,j,d] = pair + A2[b,i,d] + C2[b,j,d] + feats(i,j)·Wd2[:,d] -> d_out
// ---------------------------------------------------------------------------
__global__ __launch_bounds__(256) void k_assemble(
    const float* __restrict__ pair, const float* __restrict__ a2,
    const float* __restrict__ c2, const float* __restrict__ wd2,
    float* __restrict__ xout)
{
    size_t idx = (size_t)blockIdx.x * 256 + threadIdx.x;
    int d = (int)(idx & 127);
    size_t r = idx >> 7;
    int j = (int)(r & 255); r >>= 8;
    int i = (int)(r & 255);
    int b = (int)(r >> 8);

    float ds = fabsf((float)(i - j)) * (1.0f / 255.0f);
    float sg = (float)((i > j) - (i < j));
    float ex = __expf(-ds);

    float v = pair[idx]
            + a2[(size_t)(b * 256 + i) * 128 + d]
            + c2[(size_t)(b * 256 + j) * 128 + d]
            + ds * wd2[d] + sg * wd2[128 + d] + ex * wd2[256 + d];
    xout[idx] = v;
}

// ---------------------------------------------------------------------------
// E (MFMA attention): per (b,i) slice [256 rows x 128].
// 512 threads = 8 waves; wave w owns q-rows [32w, 32w+32).
// LDS (128 KB):
//   [0,      32768): ks  [256 key][64 d] bf16, 128B rows, swz
//   [32768,  65536): vT  [64 d][256 key] bf16, 512B rows, swz
//   [65536,  98304): ynh [128][128] bf16 (QKV) -> P rows 0-127 -> Ost [256][64]
//   [98304, 131072): qs  [256][64] bf16 (QKV) -> P rows 128-255
//   WroT [128][64] bf16 overlays ks in the epilogue.
// swizzle: byte_in_row ^= (row&7)<<4   (applied identically on write & read)
// ---------------------------------------------------------------------------
__global__ __launch_bounds__(512, 2) void k_attn_mfma(
    float* __restrict__ x,
    const float* __restrict__ rn_g, const float* __restrict__ rn_b,
    const ushort* __restrict__ wqT, const ushort* __restrict__ wkT,
    const ushort* __restrict__ wvT, const float* __restrict__ brv,
    const float* __restrict__ Wro, const float* __restrict__ bro)
{
    __shared__ __align__(16) unsigned char smem[131072];

    int tid = threadIdx.x;
    int w  = tid >> 6;
    int l  = tid & 63;
    int g  = l >> 4;      // 0..3  (k-group)
    int lr = l & 15;      // 0..15 (row/col within tile)
    size_t base = (size_t)blockIdx.x * 32768;

    float gl0 = rn_g[l], gl1 = rn_g[l + 64];
    float el0 = rn_b[l], el1 = rn_b[l + 64];

    // ================= QKV (two halves of 128 rows) =================
    for (int h = 0; h < 2; h++) {
        // --- LN: wave w handles local rows 16w..16w+15 of this half
        for (int rr = 0; rr < 16; rr++) {
            int rloc = 16 * w + rr;
            size_t ro = base + (size_t)(128 * h + rloc) * 128;
            float x0 = x[ro + l], x1 = x[ro + l + 64];
            float s = x0 + x1, q = x0 * x0 + x1 * x1;
#pragma unroll
            for (int off = 32; off; off >>= 1) { s += __shfl_xor(s, off); q += __shfl_xor(q, off); }
            float mu = s * (1.0f / 128.0f);
            float var = q * (1.0f / 128.0f) - mu * mu;
            float rs = rsqrtf(var + 1e-5f);
            int sw = (rloc & 7) << 4;
            *(ushort*)(smem + 65536 + rloc * 256 + ((2 * l) ^ sw))        = f2bf((x0 - mu) * rs * gl0 + el0);
            *(ushort*)(smem + 65536 + rloc * 256 + ((2 * (l + 64)) ^ sw)) = f2bf((x1 - mu) * rs * gl1 + el1);
        }
        // wave-local LDS RAW (cross-lane): drain LDS pipe
        asm volatile("s_waitcnt lgkmcnt(0)" ::: "memory");

        // --- A-frags from ynh (wave reads only its own rows)
        bf16x8 afr[4];
        int arow = 16 * w + lr;
#pragma unroll
        for (int kf = 0; kf < 4; kf++) {
            int ab = 65536 + arow * 256 + ((16 * g + 64 * kf) ^ ((arow & 7) << 4));
            afr[kf] = *(const bf16x8*)(smem + ab);
        }
        // --- per matrix: MFMA yn[16x128] @ W[128x64]
#pragma unroll
        for (int m = 0; m < 3; m++) {
            const ushort* wT = (m == 0) ? wqT : (m == 1) ? wkT : wvT;
            f32x4 acc[4];
#pragma unroll
            for (int nt = 0; nt < 4; nt++) acc[nt] = (f32x4){0.f, 0.f, 0.f, 0.f};
#pragma unroll
            for (int kf = 0; kf < 4; kf++) {
#pragma unroll
                for (int nt = 0; nt < 4; nt++) {
                    bf16x8 bfr = *(const bf16x8*)(wT + (lr + 16 * nt) * 128 + (8 * g + 32 * kf));
                    acc[nt] = MFMA_B16(afr[kf], bfr, acc[nt]);
                }
            }
#pragma unroll
            for (int nt = 0; nt < 4; nt++) {
                int col = lr + 16 * nt;
                float bv = (m == 2) ? brv[col] : 0.f;
#pragma unroll
                for (int i = 0; i < 4; i++) {
                    int qrow = 128 * h + 16 * w + 4 * g + i;
                    float v = acc[nt][i];
                    if (m == 0) {        // q (scale 1/8 folded, exact pow2)
                        int ad = 98304 + qrow * 128 + ((2 * col) ^ ((qrow & 7) << 4));
                        *(ushort*)(smem + ad) = f2bf(v * 0.125f);
                    } else if (m == 1) { // k
                        int ad = qrow * 128 + ((2 * col) ^ ((qrow & 7) << 4));
                        *(ushort*)(smem + ad) = f2bf(v);
                    } else {             // v -> transposed vT[d][key]
                        int ad = 32768 + col * 512 + ((2 * qrow) ^ ((col & 7) << 4));
                        *(ushort*)(smem + ad) = f2bf(v + bv);
                    }
                }
            }
        }
    }
    __syncthreads();   // qs/ks/vT complete (cross-wave)

    // ================= load Q A-frags to regs (rows 32w..32w+31) ============
    bf16x8 qf[2][2];
#pragma unroll
    for (int mt = 0; mt < 2; mt++)
#pragma unroll
        for (int kf = 0; kf < 2; kf++) {
            int qrow = 32 * w + 16 * mt + lr;
            int ab = 98304 + qrow * 128 + ((16 * g + 64 * kf) ^ ((qrow & 7) << 4));
            qf[mt][kf] = *(const bf16x8*)(smem + ab);
        }
    __syncthreads();   // qs dead; P region (overlays ynh+qs) may now be written

    // ================= flash over 2 KV-tiles of 128 keys ====================
    float m_run[2][4], l_run[2][4];
    f32x4 oacc[2][4];
#pragma unroll
    for (int mt = 0; mt < 2; mt++)
#pragma unroll
        for (int i = 0; i < 4; i++) { m_run[mt][i] = -INFINITY; l_run[mt][i] = 0.f; }
#pragma unroll
    for (int mt = 0; mt < 2; mt++)
#pragma unroll
        for (int nt = 0; nt < 4; nt++) oacc[mt][nt] = (f32x4){0.f, 0.f, 0.f, 0.f};

    for (int t = 0; t < 2; t++) {
        // ---- S = Q·K^T  (M=32 per wave, N=128, K=64)
        f32x4 sacc[2][8];
#pragma unroll
        for (int mt = 0; mt < 2; mt++)
#pragma unroll
            for (int nt = 0; nt < 8; nt++) sacc[mt][nt] = (f32x4){0.f, 0.f, 0.f, 0.f};
#pragma unroll
        for (int nt = 0; nt < 8; nt++) {
#pragma unroll
            for (int kf = 0; kf < 2; kf++) {
                int key = 128 * t + 16 * nt + lr;
                int ab = key * 128 + ((16 * g + 64 * kf) ^ ((key & 7) << 4));
                bf16x8 bfr = *(const bf16x8*)(smem + ab);
#pragma unroll
                for (int mt = 0; mt < 2; mt++)
                    sacc[mt][nt] = MFMA_B16(qf[mt][kf], bfr, sacc[mt][nt]);
            }
        }
        // ---- online softmax (rows live in 16-lane groups) + P write
#pragma unroll
        for (int mt = 0; mt < 2; mt++) {
#pragma unroll
            for (int i = 0; i < 4; i++) {
                float mx = sacc[mt][0][i];
#pragma unroll
                for (int nt = 1; nt < 8; nt++) mx = fmaxf(mx, sacc[mt][nt][i]);
#pragma unroll
                for (int off = 1; off < 16; off <<= 1) mx = fmaxf(mx, __shfl_xor(mx, off));
                float mnew = fmaxf(m_run[mt][i], mx);
                float corr = __expf(m_run[mt][i] - mnew);   // -inf -> 0
                m_run[mt][i] = mnew;
                int qrow = 32 * w + 16 * mt + 4 * g + i;
                int swq = (qrow & 7) << 4;
                float rs = 0.f;
#pragma unroll
                for (int nt = 0; nt < 8; nt++) {
                    float p = __expf(sacc[mt][nt][i] - mnew);
                    rs += p;
                    int col = lr + 16 * nt;
                    *(ushort*)(smem + 65536 + qrow * 256 + ((2 * col) ^ swq)) = f2bf(p);
                }
#pragma unroll
                for (int off = 1; off < 16; off <<= 1) rs += __shfl_xor(rs, off);
                l_run[mt][i] = l_run[mt][i] * corr + rs;
#pragma unroll
                for (int nt = 0; nt < 4; nt++) oacc[mt][nt][i] *= corr;
            }
        }
        asm volatile("s_waitcnt lgkmcnt(0)" ::: "memory");  // P cross-lane RAW

        // ---- O += P·V  (K=128)
#pragma unroll
        for (int kf = 0; kf < 4; kf++) {
            bf16x8 pfr[2];
#pragma unroll
            for (int mt = 0; mt < 2; mt++) {
                int qrow = 32 * w + 16 * mt + lr;
                int ab = 65536 + qrow * 256 + ((16 * g + 64 * kf) ^ ((qrow & 7) << 4));
                pfr[mt] = *(const bf16x8*)(smem + ab);
            }
#pragma unroll
            for (int nt = 0; nt < 4; nt++) {
                int d = lr + 16 * nt;
                int bb = 32768 + d * 512 + ((16 * g + 64 * kf + 256 * t) ^ ((d & 7) << 4));
                bf16x8 bfr = *(const bf16x8*)(smem + bb);
#pragma unroll
                for (int mt = 0; mt < 2; mt++)
                    oacc[mt][nt] = MFMA_B16(pfr[mt], bfr, oacc[mt][nt]);
            }
        }
    }
    __syncthreads();   // all waves done with P/ks/vT

    // ================= normalize, stage O + WroT ============================
#pragma unroll
    for (int mt = 0; mt < 2; mt++)
#pragma unroll
        for (int i = 0; i < 4; i++) {
            float rl = 1.0f / l_run[mt][i];
            int qrow = 32 * w + 16 * mt + 4 * g + i;
            int swq = (qrow & 7) << 4;
#pragma unroll
            for (int nt = 0; nt < 4; nt++) {
                int col = lr + 16 * nt;
                *(ushort*)(smem + 65536 + qrow * 128 + ((2 * col) ^ swq)) = f2bf(oacc[mt][nt][i] * rl);
            }
        }
    for (int e = tid; e < 8192; e += 512) {   // WroT[c][k] = Wro[k][c]
        int k = e >> 7, c = e & 127;
        int ad = c * 128 + ((2 * k) ^ ((c & 7) << 4));
        *(ushort*)(smem + ad) = f2bf(Wro[e]);
    }
    __syncthreads();

    // ================= out-proj: x += O @ Wro + bro  (M=32/wave,N=128,K=64) ==
#pragma unroll
    for (int mt = 0; mt < 2; mt++) {
        bf16x8 ofr[2];
#pragma unroll
        for (int kf = 0; kf < 2; kf++) {
            int orow = 32 * w + 16 * mt + lr;
            int ab = 65536 + orow * 128 + ((16 * g + 64 * kf) ^ ((orow & 7) << 4));
            ofr[kf] = *(const bf16x8*)(smem + ab);
        }
#pragma unroll
        for (int nt = 0; nt < 8; nt++) {
            f32x4 acc = (f32x4){0.f, 0.f, 0.f, 0.f};
#pragma unroll
            for (int kf = 0; kf < 2; kf++) {
                int c = lr + 16 * nt;
                int bb = c * 128 + ((16 * g + 64 * kf) ^ ((c & 7) << 4));
                bf16x8 bfr = *(const bf16x8*)(smem + bb);
                acc = MFMA_B16(ofr[kf], bfr, acc);
            }
            int col = lr + 16 * nt;
            float brod = bro[col];
#pragma unroll
            for (int i = 0; i < 4; i++) {
                int qrow = 32 * w + 16 * mt + 4 * g + i;
                size_t off = base + (size_t)qrow * 128 + col;
                x[off] = x[off] + acc[i] + brod;
            }
        }
    }
}

// ---------------------------------------------------------------------------
// F (tiled MLP, VALU): 16 rows/block. x += relu(LN(x)@W1+b1)@W2 + b2.
// ---------------------------------------------------------------------------
__global__ __launch_bounds__(256) void k_mlp_t(
    float* __restrict__ x, const float* __restrict__ mn_g,
    const float* __restrict__ mn_b,
    const float* __restrict__ W1, const float* __restrict__ b1,
    const float* __restrict__ W2, const float* __restrict__ b2)
{
    __shared__ ushort ynm[16 * 128];
    __shared__ ushort hbuf[16 * 256];
    int tid = threadIdx.x, w = tid >> 6, l = tid & 63;
    size_t rbase = (size_t)blockIdx.x * 16;

    {
        float gl0 = mn_g[l], gl1 = mn_g[l + 64];
        float el0 = mn_b[l], el1 = mn_b[l + 64];
#pragma unroll
        for (int rr = 0; rr < 4; rr++) {
            int lr2 = w * 4 + rr;
            size_t ro = (rbase + lr2) * 128;
            float x0 = x[ro + l], x1 = x[ro + l + 64];
            float s = x0 + x1, q = x0 * x0 + x1 * x1;
#pragma unroll
            for (int off = 32; off; off >>= 1) { s += __shfl_xor(s, off); q += __shfl_xor(q, off); }
            float mu = s * (1.0f / 128.0f);
            float var = q * (1.0f / 128.0f) - mu * mu;
            float rs = rsqrtf(var + 1e-5f);
            ynm[lr2 * 128 + l]      = f2bf((x0 - mu) * rs * gl0 + el0);
            ynm[lr2 * 128 + l + 64] = f2bf((x1 - mu) * rs * gl1 + el1);
        }
    }
    __syncthreads();

    {
        int ch = tid & 127;
        int g  = tid >> 7;
        float hb0 = b1[2 * ch], hb1 = b1[2 * ch + 1];
        float accB[16];
#pragma unroll
        for (int i = 0; i < 8; i++) { accB[i * 2] = hb0; accB[i * 2 + 1] = hb1; }
        for (int u = 0; u < 128; u += 2) {
            float wa0 = W1[(size_t)u * 256 + 2 * ch];
            float wa1 = W1[(size_t)u * 256 + 2 * ch + 1];
            float wb0 = W1[(size_t)(u + 1) * 256 + 2 * ch];
            float wb1 = W1[(size_t)(u + 1) * 256 + 2 * ch + 1];
#pragma unroll
            for (int rr = 0; rr < 8; rr++) {
                uint yv = *(const uint*)(ynm + (g * 8 + rr) * 128 + u);
                float y0 = bfraw(yv & 0xffffu), y1 = bfraw(yv >> 16);
                accB[rr * 2 + 0] += y0 * wa0 + y1 * wb0;
                accB[rr * 2 + 1] += y0 * wa1 + y1 * wb1;
            }
        }
#pragma unroll
        for (int rr = 0; rr < 8; rr++) {
            uint hp = packbf(fmaxf(accB[rr * 2], 0.f), fmaxf(accB[rr * 2 + 1], 0.f));
            *(uint*)(hbuf + (g * 8 + rr) * 256 + 2 * ch) = hp;
        }
    }
    __syncthreads();

    {
        int dh = tid & 63;
        int g2 = tid >> 6;
        float ob0 = b2[2 * dh], ob1 = b2[2 * dh + 1];
        float accC[8];
#pragma unroll
        for (int i = 0; i < 4; i++) { accC[i * 2] = ob0; accC[i * 2 + 1] = ob1; }
        for (int c = 0; c < 256; c += 2) {
            float wa0 = W2[(size_t)c * 128 + 2 * dh];
            float wa1 = W2[(size_t)c * 128 + 2 * dh + 1];
            float wb0 = W2[(size_t)(c + 1) * 128 + 2 * dh];
            float wb1 = W2[(size_t)(c + 1) * 128 + 2 * dh + 1];
#pragma unroll
            for (int rr = 0; rr < 4; rr++) {
                uint hv = *(const uint*)(hbuf + (g2 * 4 + rr) * 256 + c);
                float h0 = bfraw(hv & 0xffffu), h1 = bfraw(hv >> 16);
                accC[rr * 2 + 0] += h0 * wa0 + h1 * wb0;
                accC[rr * 2 + 1] += h0 * wa1 + h1 * wb1;
            }
        }
#pragma unroll
        for (int rr = 0; rr < 4; rr++) {
            size_t off = (rbase + g2 * 4 + rr) * 128 + 2 * dh;
            x[off]     += accC[rr * 2 + 0];
            x[off + 1] += accC[rr * 2 + 1];
        }
    }
}

// ---------------------------------------------------------------------------
extern "C" void kernel_launch(void* const* d_in, const int* in_sizes, int n_in,
                              void* d_out, int out_size, void* d_ws, size_t ws_size,
                              hipStream_t stream)
{
    const float* seq   = (const float*)d_in[0];
    const float* pair  = (const float*)d_in[1];
    const float* sn_g  = (const float*)d_in[2];
    const float* sn_b  = (const float*)d_in[3];
    const float* Wq    = (const float*)d_in[4];
    const float* Wk    = (const float*)d_in[5];
    const float* Wyq   = (const float*)d_in[6];
    const float* Wyk   = (const float*)d_in[7];
    const float* Wdist = (const float*)d_in[8];
    const float* Wout  = (const float*)d_in[9];
    const float* bout  = (const float*)d_in[10];
    const float* rn_g  = (const float*)d_in[11];
    const float* rn_b  = (const float*)d_in[12];
    const float* Wrq   = (const float*)d_in[13];
    const float* Wrk   = (const float*)d_in[14];
    const float* Wrv   = (const float*)d_in[15];
    const float* brv   = (const float*)d_in[16];
    const float* Wro   = (const float*)d_in[17];
    const float* bro   = (const float*)d_in[18];
    const float* mn_g  = (const float*)d_in[19];
    const float* mn_b  = (const float*)d_in[20];
    const float* W1    = (const float*)d_in[21];
    const float* b1    = (const float*)d_in[22];
    const float* W2    = (const float*)d_in[23];
    const float* b2    = (const float*)d_in[24];
    (void)in_sizes; (void)n_in; (void)out_size; (void)ws_size;

    // ws: ~1.6 MB used
    float*  x2   = (float*)d_ws;          // [2,256,512]  262144 f32
    float*  a2   = x2 + 262144;           // [2,256,128]   65536 f32
    float*  c2   = a2 + 65536;            // [2,256,128]   65536 f32
    float*  wd2  = c2 + 65536;            // [3,128]+pad     512 f32
    ushort* wqT  = (ushort*)(wd2 + 512);  // [64][128] bf16 8192
    ushort* wkT  = wqT + 8192;
    ushort* wvT  = wkT + 8192;
    float*  xres = (float*)d_out;

    k_ln_pool  <<<512,   256, 0, stream>>>(seq, sn_g, sn_b, x2);
    k_proj     <<<512,   128, 0, stream>>>(x2, Wq, Wk, Wyq, Wyk, Wout, bout, a2, c2);
    k_wd2      <<<1,     128, 0, stream>>>(Wdist, Wout, wd2);
    k_wt       <<<48,    512, 0, stream>>>(Wrq, Wrk, Wrv, wqT, wkT, wvT);
    k_assemble <<<65536, 256, 0, stream>>>(pair, a2, c2, wd2, xres);
    k_attn_mfma<<<512,   512, 0, stream>>>(xres, rn_g, rn_b, wqT, wkT, wvT, brv, Wro, bro);
    k_mlp_t    <<<8192,  256, 0, stream>>>(xres, mn_g, mn_b, W1, b1, W2, b2);
}

// Round 7
// 345.042 us; speedup vs baseline: 3.1148x; 1.7292x over previous
//
#include <hip/hip_runtime.h>
#include <hip/hip_bf16.h>

using bf16 = __hip_bfloat16;
typedef unsigned int uint;
typedef unsigned short ushort;
typedef __attribute__((ext_vector_type(8))) short bf16x8;
typedef __attribute__((ext_vector_type(4))) float f32x4;

// Shapes: B=2, S=512, SD=512, P=256, PD=128, AD=64, H=256
// All global tensors are f32 (verified: WRITE_SIZE of full-tensor store = 4B/elem).

__device__ __forceinline__ float bfraw(uint u) { return __uint_as_float(u << 16); }
__device__ __forceinline__ ushort f2bf(float f) {
    bf16 h = __float2bfloat16(f);
    return *reinterpret_cast<ushort*>(&h);
}

#define MFMA_B16(a, b, c) __builtin_amdgcn_mfma_f32_16x16x32_bf16((a), (b), (c), 0, 0, 0)

// ---------------------------------------------------------------------------
// A: LayerNorm(seq) over SD=512 + avg-pool row pairs -> x2 f32. 512 blocks.
// ---------------------------------------------------------------------------
__global__ __launch_bounds__(256) void k_ln_pool(
    const float* __restrict__ seq, const float* __restrict__ g,
    const float* __restrict__ be, float* __restrict__ x2)
{
    __shared__ float red[4][4];
    int bp = blockIdx.x;
    int t  = threadIdx.x;
    const float* r0 = seq + (size_t)(bp * 2) * 512;
    const float* r1 = r0 + 512;

    float a0 = r0[t], a1 = r0[t + 256];
    float c0 = r1[t], c1 = r1[t + 256];

    float s0 = a0 + a1, q0 = a0 * a0 + a1 * a1;
    float s1 = c0 + c1, q1 = c0 * c0 + c1 * c1;
#pragma unroll
    for (int off = 32; off; off >>= 1) {
        s0 += __shfl_xor(s0, off); q0 += __shfl_xor(q0, off);
        s1 += __shfl_xor(s1, off); q1 += __shfl_xor(q1, off);
    }
    int w = t >> 6, l = t & 63;
    if (l == 0) { red[0][w] = s0; red[1][w] = q0; red[2][w] = s1; red[3][w] = q1; }
    __syncthreads();
    s0 = red[0][0] + red[0][1] + red[0][2] + red[0][3];
    q0 = red[1][0] + red[1][1] + red[1][2] + red[1][3];
    s1 = red[2][0] + red[2][1] + red[2][2] + red[2][3];
    q1 = red[3][0] + red[3][1] + red[3][2] + red[3][3];

    const float inv = 1.0f / 512.0f;
    float mu0 = s0 * inv, var0 = q0 * inv - mu0 * mu0, rs0 = rsqrtf(var0 + 1e-5f);
    float mu1 = s1 * inv, var1 = q1 * inv - mu1 * mu1, rs1 = rsqrtf(var1 + 1e-5f);

    float g0 = g[t], g1 = g[t + 256];
    float e0 = be[t], e1 = be[t + 256];

    float o0 = 0.5f * ((a0 - mu0) * rs0 * g0 + e0 + (c0 - mu1) * rs1 * g0 + e0);
    float o1 = 0.5f * ((a1 - mu0) * rs0 * g1 + e1 + (c1 - mu1) * rs1 * g1 + e1);

    float* xo = x2 + (size_t)bp * 512;
    xo[t] = o0; xo[t + 256] = o1;
}

// ---------------------------------------------------------------------------
// B: A2 = (x@Wq + gelu(x)@Wyq)@Wout + bout ; C2 = (x@Wk + gelu(x)@Wyk)@Wout
// ---------------------------------------------------------------------------
__global__ __launch_bounds__(128) void k_proj(
    const float* __restrict__ x2,
    const float* __restrict__ Wq, const float* __restrict__ Wk,
    const float* __restrict__ Wyq, const float* __restrict__ Wyk,
    const float* __restrict__ Wout, const float* __restrict__ bout,
    float* __restrict__ a2, float* __restrict__ c2)
{
    __shared__ float xr[512], gxr[512], ar[128], cr[128];
    int row = blockIdx.x;
    int t   = threadIdx.x;

    for (int u = t; u < 512; u += 128) {
        float v = x2[(size_t)row * 512 + u];
        xr[u]  = v;
        gxr[u] = 0.5f * v * (1.0f + erff(v * 0.70710678118654752f));
    }
    __syncthreads();

    float a = 0.f, c = 0.f;
    for (int s = 0; s < 512; s++) {
        float xs = xr[s], gs = gxr[s];
        a += xs * Wq[s * 128 + t] + gs * Wyq[s * 128 + t];
        c += xs * Wk[s * 128 + t] + gs * Wyk[s * 128 + t];
    }
    ar[t] = a; cr[t] = c;
    __syncthreads();

    float A = bout[t], C = 0.f;
    for (int u = 0; u < 128; u++) {
        float wv = Wout[u * 128 + t];
        A += ar[u] * wv;
        C += cr[u] * wv;
    }
    a2[(size_t)row * 128 + t] = A;
    c2[(size_t)row * 128 + t] = C;
}

// ---------------------------------------------------------------------------
// W: Wd2 = Wdist(3x128) @ Wout(128x128)
// ---------------------------------------------------------------------------
__global__ __launch_bounds__(128) void k_wd2(
    const float* __restrict__ Wdist, const float* __restrict__ Wout,
    float* __restrict__ wd2)
{
    int t = threadIdx.x;
#pragma unroll
    for (int f = 0; f < 3; f++) {
        float acc = 0.f;
        for (int u = 0; u < 128; u++)
            acc += Wdist[f * 128 + u] * Wout[u * 128 + t];
        wd2[f * 128 + t] = acc;
    }
}

// ---------------------------------------------------------------------------
// WT prep: wT[c][k] (bf16, [64][128]) = W[k][c] (f32, [128][64]) for Wrq/Wrk/Wrv
// ---------------------------------------------------------------------------
__global__ __launch_bounds__(512) void k_wt(
    const float* __restrict__ Wrq, const float* __restrict__ Wrk,
    const float* __restrict__ Wrv, ushort* __restrict__ wqT,
    ushort* __restrict__ wkT, ushort* __restrict__ wvT)
{
    int idx = blockIdx.x * 512 + threadIdx.x;       // 0 .. 3*8192
    int m = idx >> 13;
    int e = idx & 8191;
    int c = e >> 7, k = e & 127;
    const float* W = (m == 0) ? Wrq : (m == 1) ? Wrk : Wrv;
    ushort* T = (m == 0) ? wqT : (m == 1) ? wkT : wvT;
    T[e] = f2bf(W[k * 64 + c]);
}

// ---------------------------------------------------------------------------
// WT prep 2 (MLP): w1T[c][k] = W1[k][c] (c<256,k<128); w2T[c][k] = W2[k][c]
// (c<128,k<256). 65536 threads total.
// ---------------------------------------------------------------------------
__global__ __launch_bounds__(512) void k_wt12(
    const float* __restrict__ W1, const float* __restrict__ W2,
    ushort* __restrict__ w1T, ushort* __restrict__ w2T)
{
    int idx = blockIdx.x * 512 + threadIdx.x;   // 0 .. 65536
    if (idx < 32768) {
        int c = idx >> 7, k = idx & 127;        // W1 [128][256] -> w1T [256][128]
        w1T[idx] = f2bf(W1[k * 256 + c]);
    } else {
        int e = idx - 32768;
        int c = e >> 8, k = e & 255;            // W2 [256][128] -> w2T [128][256]
        w2T[e] = f2bf(W2[k * 128 + c]);
    }
}

// ---------------------------------------------------------------------------
// C: x[b,i,j,d] = pair + A2[b,i,d] + C2[b,j,d] + feats(i,j)·Wd2[:,d] -> d_out
// ---------------------------------------------------------------------------
__global__ __launch_bounds__(256) void k_assemble(
    const float* __restrict__ pair, const float* __restrict__ a2,
    const float* __restrict__ c2, const float* __restrict__ wd2,
    float* __restrict__ xout)
{
    size_t idx = (size_t)blockIdx.x * 256 + threadIdx.x;
    int d = (int)(idx & 127);
    size_t r = idx >> 7;
    int j = (int)(r & 255); r >>= 8;
    int i = (int)(r & 255);
    int b = (int)(r >> 8);

    float ds = fabsf((float)(i - j)) * (1.0f / 255.0f);
    float sg = (float)((i > j) - (i < j));
    float ex = __expf(-ds);

    float v = pair[idx]
            + a2[(size_t)(b * 256 + i) * 128 + d]
            + c2[(size_t)(b * 256 + j) * 128 + d]
            + ds * wd2[d] + sg * wd2[128 + d] + ex * wd2[256 + d];
    xout[idx] = v;
}

// ---------------------------------------------------------------------------
// E (MFMA attention): per (b,i) slice [256 rows x 128].
// 512 threads = 8 waves; wave w owns q-rows [32w, 32w+32).
// LDS (128 KB):
//   [0,      32768): ks  [256 key][64 d] bf16, 128B rows, swz
//   [32768,  65536): vT  [64 d][256 key] bf16, 512B rows, swz
//   [65536,  98304): ynh [128][128] bf16 (QKV) -> P rows 0-127 -> Ost [256][64]
//   [98304, 131072): qs  [256][64] bf16 (QKV) -> P rows 128-255
//   WroT [128][64] bf16 overlays ks in the epilogue.
// swizzle: byte_in_row ^= (row&7)<<4   (applied identically on write & read)
// ---------------------------------------------------------------------------
__global__ __launch_bounds__(512, 2) void k_attn_mfma(
    float* __restrict__ x,
    const float* __restrict__ rn_g, const float* __restrict__ rn_b,
    const ushort* __restrict__ wqT, const ushort* __restrict__ wkT,
    const ushort* __restrict__ wvT, const float* __restrict__ brv,
    const float* __restrict__ Wro, const float* __restrict__ bro)
{
    __shared__ __align__(16) unsigned char smem[131072];

    int tid = threadIdx.x;
    int w  = tid >> 6;
    int l  = tid & 63;
    int g  = l >> 4;      // 0..3  (k-group)
    int lr = l & 15;      // 0..15 (row/col within tile)
    size_t base = (size_t)blockIdx.x * 32768;

    float gl0 = rn_g[l], gl1 = rn_g[l + 64];
    float el0 = rn_b[l], el1 = rn_b[l + 64];

    // ================= QKV (two halves of 128 rows) =================
    for (int h = 0; h < 2; h++) {
        // --- LN: wave w handles local rows 16w..16w+15 of this half
        for (int rr = 0; rr < 16; rr++) {
            int rloc = 16 * w + rr;
            size_t ro = base + (size_t)(128 * h + rloc) * 128;
            float x0 = x[ro + l], x1 = x[ro + l + 64];
            float s = x0 + x1, q = x0 * x0 + x1 * x1;
#pragma unroll
            for (int off = 32; off; off >>= 1) { s += __shfl_xor(s, off); q += __shfl_xor(q, off); }
            float mu = s * (1.0f / 128.0f);
            float var = q * (1.0f / 128.0f) - mu * mu;
            float rs = rsqrtf(var + 1e-5f);
            int sw = (rloc & 7) << 4;
            *(ushort*)(smem + 65536 + rloc * 256 + ((2 * l) ^ sw))        = f2bf((x0 - mu) * rs * gl0 + el0);
            *(ushort*)(smem + 65536 + rloc * 256 + ((2 * (l + 64)) ^ sw)) = f2bf((x1 - mu) * rs * gl1 + el1);
        }
        // wave-local LDS RAW (cross-lane): drain LDS pipe
        asm volatile("s_waitcnt lgkmcnt(0)" ::: "memory");

        // --- A-frags from ynh (wave reads only its own rows)
        bf16x8 afr[4];
        int arow = 16 * w + lr;
#pragma unroll
        for (int kf = 0; kf < 4; kf++) {
            int ab = 65536 + arow * 256 + ((16 * g + 64 * kf) ^ ((arow & 7) << 4));
            afr[kf] = *(const bf16x8*)(smem + ab);
        }
        // --- per matrix: MFMA yn[16x128] @ W[128x64]
#pragma unroll
        for (int m = 0; m < 3; m++) {
            const ushort* wT = (m == 0) ? wqT : (m == 1) ? wkT : wvT;
            f32x4 acc[4];
#pragma unroll
            for (int nt = 0; nt < 4; nt++) acc[nt] = (f32x4){0.f, 0.f, 0.f, 0.f};
#pragma unroll
            for (int kf = 0; kf < 4; kf++) {
#pragma unroll
                for (int nt = 0; nt < 4; nt++) {
                    bf16x8 bfr = *(const bf16x8*)(wT + (lr + 16 * nt) * 128 + (8 * g + 32 * kf));
                    acc[nt] = MFMA_B16(afr[kf], bfr, acc[nt]);
                }
            }
#pragma unroll
            for (int nt = 0; nt < 4; nt++) {
                int col = lr + 16 * nt;
                float bv = (m == 2) ? brv[col] : 0.f;
#pragma unroll
                for (int i = 0; i < 4; i++) {
                    int qrow = 128 * h + 16 * w + 4 * g + i;
                    float v = acc[nt][i];
                    if (m == 0) {        // q (scale 1/8 folded, exact pow2)
                        int ad = 98304 + qrow * 128 + ((2 * col) ^ ((qrow & 7) << 4));
                        *(ushort*)(smem + ad) = f2bf(v * 0.125f);
                    } else if (m == 1) { // k
                        int ad = qrow * 128 + ((2 * col) ^ ((qrow & 7) << 4));
                        *(ushort*)(smem + ad) = f2bf(v);
                    } else {             // v -> transposed vT[d][key]
                        int ad = 32768 + col * 512 + ((2 * qrow) ^ ((col & 7) << 4));
                        *(ushort*)(smem + ad) = f2bf(v + bv);
                    }
                }
            }
        }
    }
    __syncthreads();   // qs/ks/vT complete (cross-wave)

    // ================= load Q A-frags to regs (rows 32w..32w+31) ============
    bf16x8 qf[2][2];
#pragma unroll
    for (int mt = 0; mt < 2; mt++)
#pragma unroll
        for (int kf = 0; kf < 2; kf++) {
            int qrow = 32 * w + 16 * mt + lr;
            int ab = 98304 + qrow * 128 + ((16 * g + 64 * kf) ^ ((qrow & 7) << 4));
            qf[mt][kf] = *(const bf16x8*)(smem + ab);
        }
    __syncthreads();   // qs dead; P region (overlays ynh+qs) may now be written

    // ================= flash over 2 KV-tiles of 128 keys ====================
    float m_run[2][4], l_run[2][4];
    f32x4 oacc[2][4];
#pragma unroll
    for (int mt = 0; mt < 2; mt++)
#pragma unroll
        for (int i = 0; i < 4; i++) { m_run[mt][i] = -INFINITY; l_run[mt][i] = 0.f; }
#pragma unroll
    for (int mt = 0; mt < 2; mt++)
#pragma unroll
        for (int nt = 0; nt < 4; nt++) oacc[mt][nt] = (f32x4){0.f, 0.f, 0.f, 0.f};

    for (int t = 0; t < 2; t++) {
        // ---- S = Q·K^T  (M=32 per wave, N=128, K=64)
        f32x4 sacc[2][8];
#pragma unroll
        for (int mt = 0; mt < 2; mt++)
#pragma unroll
            for (int nt = 0; nt < 8; nt++) sacc[mt][nt] = (f32x4){0.f, 0.f, 0.f, 0.f};
#pragma unroll
        for (int nt = 0; nt < 8; nt++) {
#pragma unroll
            for (int kf = 0; kf < 2; kf++) {
                int key = 128 * t + 16 * nt + lr;
                int ab = key * 128 + ((16 * g + 64 * kf) ^ ((key & 7) << 4));
                bf16x8 bfr = *(const bf16x8*)(smem + ab);
#pragma unroll
                for (int mt = 0; mt < 2; mt++)
                    sacc[mt][nt] = MFMA_B16(qf[mt][kf], bfr, sacc[mt][nt]);
            }
        }
        // ---- online softmax (rows live in 16-lane groups) + P write
#pragma unroll
        for (int mt = 0; mt < 2; mt++) {
#pragma unroll
            for (int i = 0; i < 4; i++) {
                float mx = sacc[mt][0][i];
#pragma unroll
                for (int nt = 1; nt < 8; nt++) mx = fmaxf(mx, sacc[mt][nt][i]);
#pragma unroll
                for (int off = 1; off < 16; off <<= 1) mx = fmaxf(mx, __shfl_xor(mx, off));
                float mnew = fmaxf(m_run[mt][i], mx);
                float corr = __expf(m_run[mt][i] - mnew);   // -inf -> 0
                m_run[mt][i] = mnew;
                int qrow = 32 * w + 16 * mt + 4 * g + i;
                int swq = (qrow & 7) << 4;
                float rs = 0.f;
#pragma unroll
                for (int nt = 0; nt < 8; nt++) {
                    float p = __expf(sacc[mt][nt][i] - mnew);
                    rs += p;
                    int col = lr + 16 * nt;
                    *(ushort*)(smem + 65536 + qrow * 256 + ((2 * col) ^ swq)) = f2bf(p);
                }
#pragma unroll
                for (int off = 1; off < 16; off <<= 1) rs += __shfl_xor(rs, off);
                l_run[mt][i] = l_run[mt][i] * corr + rs;
#pragma unroll
                for (int nt = 0; nt < 4; nt++) oacc[mt][nt][i] *= corr;
            }
        }
        asm volatile("s_waitcnt lgkmcnt(0)" ::: "memory");  // P cross-lane RAW

        // ---- O += P·V  (K=128)
#pragma unroll
        for (int kf = 0; kf < 4; kf++) {
            bf16x8 pfr[2];
#pragma unroll
            for (int mt = 0; mt < 2; mt++) {
                int qrow = 32 * w + 16 * mt + lr;
                int ab = 65536 + qrow * 256 + ((16 * g + 64 * kf) ^ ((qrow & 7) << 4));
                pfr[mt] = *(const bf16x8*)(smem + ab);
            }
#pragma unroll
            for (int nt = 0; nt < 4; nt++) {
                int d = lr + 16 * nt;
                int bb = 32768 + d * 512 + ((16 * g + 64 * kf + 256 * t) ^ ((d & 7) << 4));
                bf16x8 bfr = *(const bf16x8*)(smem + bb);
#pragma unroll
                for (int mt = 0; mt < 2; mt++)
                    oacc[mt][nt] = MFMA_B16(pfr[mt], bfr, oacc[mt][nt]);
            }
        }
    }
    __syncthreads();   // all waves done with P/ks/vT

    // ================= normalize, stage O + WroT ============================
#pragma unroll
    for (int mt = 0; mt < 2; mt++)
#pragma unroll
        for (int i = 0; i < 4; i++) {
            float rl = 1.0f / l_run[mt][i];
            int qrow = 32 * w + 16 * mt + 4 * g + i;
            int swq = (qrow & 7) << 4;
#pragma unroll
            for (int nt = 0; nt < 4; nt++) {
                int col = lr + 16 * nt;
                *(ushort*)(smem + 65536 + qrow * 128 + ((2 * col) ^ swq)) = f2bf(oacc[mt][nt][i] * rl);
            }
        }
    for (int e = tid; e < 8192; e += 512) {   // WroT[c][k] = Wro[k][c]
        int k = e >> 7, c = e & 127;
        int ad = c * 128 + ((2 * k) ^ ((c & 7) << 4));
        *(ushort*)(smem + ad) = f2bf(Wro[e]);
    }
    __syncthreads();

    // ================= out-proj: x += O @ Wro + bro  (M=32/wave,N=128,K=64) ==
#pragma unroll
    for (int mt = 0; mt < 2; mt++) {
        bf16x8 ofr[2];
#pragma unroll
        for (int kf = 0; kf < 2; kf++) {
            int orow = 32 * w + 16 * mt + lr;
            int ab = 65536 + orow * 128 + ((16 * g + 64 * kf) ^ ((orow & 7) << 4));
            ofr[kf] = *(const bf16x8*)(smem + ab);
        }
#pragma unroll
        for (int nt = 0; nt < 8; nt++) {
            f32x4 acc = (f32x4){0.f, 0.f, 0.f, 0.f};
#pragma unroll
            for (int kf = 0; kf < 2; kf++) {
                int c = lr + 16 * nt;
                int bb = c * 128 + ((16 * g + 64 * kf) ^ ((c & 7) << 4));
                bf16x8 bfr = *(const bf16x8*)(smem + bb);
                acc = MFMA_B16(ofr[kf], bfr, acc);
            }
            int col = lr + 16 * nt;
            float brod = bro[col];
#pragma unroll
            for (int i = 0; i < 4; i++) {
                int qrow = 32 * w + 16 * mt + 4 * g + i;
                size_t off = base + (size_t)qrow * 128 + col;
                x[off] = x[off] + acc[i] + brod;
            }
        }
    }
}

// ---------------------------------------------------------------------------
// F (MFMA MLP): 128 rows/block, 1024 blocks, 256 threads (4 waves).
// x += relu(LN(x)@W1+b1)@W2 + b2.  H=256 split into two halves of 128.
// LDS (64 KB): yn [128][128] bf16 @0, h [128][128] bf16 @32768 (swizzled rows).
// Wave w owns rows [32w, 32w+32). B-frags stream from L2-resident w1T/w2T.
// ---------------------------------------------------------------------------
__global__ __launch_bounds__(256, 2) void k_mlp_mfma(
    float* __restrict__ x,
    const float* __restrict__ mn_g, const float* __restrict__ mn_b,
    const ushort* __restrict__ w1T, const ushort* __restrict__ w2T,
    const float* __restrict__ b1, const float* __restrict__ b2)
{
    __shared__ __align__(16) unsigned char smem[65536];
    int tid = threadIdx.x;
    int w = tid >> 6, l = tid & 63;
    int g = l >> 4, lr = l & 15;
    size_t rbase = (size_t)blockIdx.x * 128;

    // ---- LN: wave w -> rows 32w..32w+31 -> yn LDS (bf16, swz)
    {
        float gl0 = mn_g[l], gl1 = mn_g[l + 64];
        float el0 = mn_b[l], el1 = mn_b[l + 64];
        for (int rr = 0; rr < 32; rr++) {
            int rloc = 32 * w + rr;
            size_t ro = (rbase + rloc) * 128;
            float x0 = x[ro + l], x1 = x[ro + l + 64];
            float s = x0 + x1, q = x0 * x0 + x1 * x1;
#pragma unroll
            for (int off = 32; off; off >>= 1) { s += __shfl_xor(s, off); q += __shfl_xor(q, off); }
            float mu = s * (1.0f / 128.0f);
            float var = q * (1.0f / 128.0f) - mu * mu;
            float rs = rsqrtf(var + 1e-5f);
            int sw = (rloc & 7) << 4;
            *(ushort*)(smem + rloc * 256 + ((2 * l) ^ sw))        = f2bf((x0 - mu) * rs * gl0 + el0);
            *(ushort*)(smem + rloc * 256 + ((2 * (l + 64)) ^ sw)) = f2bf((x1 - mu) * rs * gl1 + el1);
        }
    }
    __syncthreads();

    // ---- A-frags of yn (rows 32w+16mt+lr), persistent across both halves
    bf16x8 afr[2][4];
#pragma unroll
    for (int mt = 0; mt < 2; mt++)
#pragma unroll
        for (int kf = 0; kf < 4; kf++) {
            int row = 32 * w + 16 * mt + lr;
            afr[mt][kf] = *(const bf16x8*)(smem + row * 256 + ((16 * g + 64 * kf) ^ ((row & 7) << 4)));
        }

    f32x4 oacc[2][8];
#pragma unroll
    for (int mt = 0; mt < 2; mt++)
#pragma unroll
        for (int nt = 0; nt < 8; nt++) oacc[mt][nt] = (f32x4){0.f, 0.f, 0.f, 0.f};

    for (int kb = 0; kb < 2; kb++) {
        // ---- stage 1: h = relu(yn @ W1[:,128kb:128kb+128] + b1half)
#pragma unroll
        for (int mt = 0; mt < 2; mt++) {
#pragma unroll
            for (int nt = 0; nt < 8; nt++) {
                f32x4 acc = (f32x4){0.f, 0.f, 0.f, 0.f};
#pragma unroll
                for (int kf = 0; kf < 4; kf++) {
                    bf16x8 bfr = *(const bf16x8*)(w1T + (size_t)(128 * kb + 16 * nt + lr) * 128 + (32 * kf + 8 * g));
                    acc = MFMA_B16(afr[mt][kf], bfr, acc);
                }
                int col = 16 * nt + lr;
                float bb = b1[128 * kb + col];
#pragma unroll
                for (int i = 0; i < 4; i++) {
                    int row = 32 * w + 16 * mt + 4 * g + i;
                    int ad = 32768 + row * 256 + ((2 * col) ^ ((row & 7) << 4));
                    *(ushort*)(smem + ad) = f2bf(fmaxf(acc[i] + bb, 0.f));
                }
            }
        }
        __syncthreads();   // h ready

        // ---- stage 2: oacc += h @ W2[128kb:128kb+128, :]
#pragma unroll
        for (int mt = 0; mt < 2; mt++) {
            bf16x8 hfr[4];
#pragma unroll
            for (int kf = 0; kf < 4; kf++) {
                int row = 32 * w + 16 * mt + lr;
                hfr[kf] = *(const bf16x8*)(smem + 32768 + row * 256 + ((16 * g + 64 * kf) ^ ((row & 7) << 4)));
            }
#pragma unroll
            for (int nt = 0; nt < 8; nt++) {
#pragma unroll
                for (int kf = 0; kf < 4; kf++) {
                    bf16x8 bfr = *(const bf16x8*)(w2T + (size_t)(16 * nt + lr) * 256 + (128 * kb + 32 * kf + 8 * g));
                    oacc[mt][nt] = MFMA_B16(hfr[kf], bfr, oacc[mt][nt]);
                }
            }
        }
        __syncthreads();   // h consumed; safe to overwrite next half
    }

    // ---- epilogue: x += oacc + b2
#pragma unroll
    for (int mt = 0; mt < 2; mt++)
#pragma unroll
        for (int nt = 0; nt < 8; nt++) {
            int col = 16 * nt + lr;
            float bb = b2[col];
#pragma unroll
            for (int i = 0; i < 4; i++) {
                int row = 32 * w + 16 * mt + 4 * g + i;
                size_t off = (rbase + row) * 128 + col;
                x[off] = x[off] + oacc[mt][nt][i] + bb;
            }
        }
}

// ---------------------------------------------------------------------------
extern "C" void kernel_launch(void* const* d_in, const int* in_sizes, int n_in,
                              void* d_out, int out_size, void* d_ws, size_t ws_size,
                              hipStream_t stream)
{
    const float* seq   = (const float*)d_in[0];
    const float* pair  = (const float*)d_in[1];
    const float* sn_g  = (const float*)d_in[2];
    const float* sn_b  = (const float*)d_in[3];
    const float* Wq    = (const float*)d_in[4];
    const float* Wk    = (const float*)d_in[5];
    const float* Wyq   = (const float*)d_in[6];
    const float* Wyk   = (const float*)d_in[7];
    const float* Wdist = (const float*)d_in[8];
    const float* Wout  = (const float*)d_in[9];
    const float* bout  = (const float*)d_in[10];
    const float* rn_g  = (const float*)d_in[11];
    const float* rn_b  = (const float*)d_in[12];
    const float* Wrq   = (const float*)d_in[13];
    const float* Wrk   = (const float*)d_in[14];
    const float* Wrv   = (const float*)d_in[15];
    const float* brv   = (const float*)d_in[16];
    const float* Wro   = (const float*)d_in[17];
    const float* bro   = (const float*)d_in[18];
    const float* mn_g  = (const float*)d_in[19];
    const float* mn_b  = (const float*)d_in[20];
    const float* W1    = (const float*)d_in[21];
    const float* b1    = (const float*)d_in[22];
    const float* W2    = (const float*)d_in[23];
    const float* b2    = (const float*)d_in[24];
    (void)in_sizes; (void)n_in; (void)out_size; (void)ws_size;

    // ws: ~1.75 MB used
    float*  x2   = (float*)d_ws;          // [2,256,512]  262144 f32
    float*  a2   = x2 + 262144;           // [2,256,128]   65536 f32
    float*  c2   = a2 + 65536;            // [2,256,128]   65536 f32
    float*  wd2  = c2 + 65536;            // [3,128]+pad     512 f32
    ushort* wqT  = (ushort*)(wd2 + 512);  // [64][128] bf16 8192
    ushort* wkT  = wqT + 8192;
    ushort* wvT  = wkT + 8192;
    ushort* w1T  = wvT + 8192;            // [256][128] bf16 32768
    ushort* w2T  = w1T + 32768;           // [128][256] bf16 32768
    float*  xres = (float*)d_out;

    k_ln_pool  <<<512,   256, 0, stream>>>(seq, sn_g, sn_b, x2);
    k_proj     <<<512,   128, 0, stream>>>(x2, Wq, Wk, Wyq, Wyk, Wout, bout, a2, c2);
    k_wd2      <<<1,     128, 0, stream>>>(Wdist, Wout, wd2);
    k_wt       <<<48,    512, 0, stream>>>(Wrq, Wrk, Wrv, wqT, wkT, wvT);
    k_wt12     <<<128,   512, 0, stream>>>(W1, W2, w1T, w2T);
    k_assemble <<<65536, 256, 0, stream>>>(pair, a2, c2, wd2, xres);
    k_attn_mfma<<<512,   512, 0, stream>>>(xres, rn_g, rn_b, wqT, wkT, wvT, brv, Wro, bro);
    k_mlp_mfma <<<1024,  256, 0, stream>>>(xres, mn_g, mn_b, w1T, w2T, b1, b2);
}